// Round 1
// baseline (3946.989 us; speedup 1.0000x reference)
//
#include <hip/hip_runtime.h>
#include <math.h>

#define B 128
#define S 512
#define E 128
#define R 256
#define G4 1024  // 4*R

// ---- workspace layout (float offsets) ----
// HSfull: [513][R/4][B][4] floats  (slot 0 = h_{-1} = zeros; step t reads slot t, writes slot t+1)
static const size_t HS_FLOATS = 513ull * R * B;            // 16,809,984
static const size_t C_OFF     = HS_FLOATS;                 // c: [R][B]
static const size_t X4_OFF    = C_OFF + (size_t)R * B;     // X: [S][E/4][B][4]
static const size_t WUT_OFF   = X4_OFF + (size_t)S * E * B;// WUt: [G4][384]
static const size_t WS_FLOATS = WUT_OFF + (size_t)G4 * 384;

// probs output is [B][S][9]; h_last at +589824, c_last at +622592
#define HOUT_OFF 589824
#define COUT_OFF 622592

__global__ void zero_state(float4* __restrict__ hs0, float4* __restrict__ c4) {
    int i = blockIdx.x * 256 + threadIdx.x;   // 64 blocks * 256 = 16384 threads
    float4 z = make_float4(0.f, 0.f, 0.f, 0.f);
    if (i < 8192) hs0[i] = z;                 // HS slot 0: R*B = 32768 floats = 8192 float4
    else          c4[i - 8192] = z;           // c: 8192 float4
}

// X4[t][e4][b] = embed[idx[b][t]][e4]   (float4 granularity, b contiguous for coalescing)
__global__ void gather_x(const int* __restrict__ idx, const float* __restrict__ embed,
                         float4* __restrict__ X4) {
    int t    = blockIdx.x;
    int tid  = threadIdx.x;          // 256
    int b    = tid & 127;
    int half = tid >> 7;
    int row  = idx[(size_t)b * S + t];
    const float4* er = (const float4*)embed + (size_t)row * (E / 4);
    size_t xbase = (size_t)t * (E / 4) * B + b;
#pragma unroll
    for (int kk = 0; kk < 16; ++kk) {
        int e4 = half * 16 + kk;
        X4[xbase + (size_t)e4 * B] = er[e4];
    }
}

// WUt[j][s] : s<128 -> W[s][j], else U[s-128][j]   (row per gate-column, contiguous for s_load)
__global__ void make_wut(const float* __restrict__ W, const float* __restrict__ U,
                         float* __restrict__ WUt) {
    int j = blockIdx.x;
    int s = threadIdx.x;             // 384
    float v = (s < E) ? W[(size_t)s * G4 + j] : U[(size_t)(s - E) * G4 + j];
    WUt[(size_t)j * 384 + s] = v;
}

// One timestep. grid = dim3(R/2, 2), block = 256 (4 waves).
// wave wid: rl = wid>>1 (which of 2 hidden units in this block), k = wid&1 (splitK half)
// k0: s in [0,192)  = all of x@W (128) + h@U r'=[0,64)
// k1: s in [192,384) = h@U r'=[64,256)
__launch_bounds__(256, 1)
__global__ void lstm_step(const float4* __restrict__ X4, const float* __restrict__ WUt,
                          const float* __restrict__ bias, float* __restrict__ HS,
                          float* __restrict__ cbuf, float* __restrict__ out, int t) {
    __shared__ float partial[2][4][64];
    int lane = threadIdx.x & 63;
    int wid  = __builtin_amdgcn_readfirstlane((int)(threadIdx.x >> 6));
    int k    = wid & 1;
    int rl   = wid >> 1;
    int r    = blockIdx.x * 2 + rl;   // hidden unit
    int bg   = blockIdx.y;
    int b    = bg * 64 + lane;        // batch lane

    const float* wu0 = WUt + (size_t)(0 * R + r) * 384;  // i
    const float* wu1 = WUt + (size_t)(1 * R + r) * 384;  // f
    const float* wu2 = WUt + (size_t)(2 * R + r) * 384;  // g
    const float* wu3 = WUt + (size_t)(3 * R + r) * 384;  // o

    float a0, a1, a2, a3;
    if (k == 0) { a0 = bias[r]; a1 = bias[R + r]; a2 = bias[2 * R + r]; a3 = bias[3 * R + r]; }
    else        { a0 = a1 = a2 = a3 = 0.f; }

    const float4* hs_in = (const float4*)HS + (size_t)t * (R / 4) * B + b;

    if (k == 0) {
        const float4* xp = X4 + (size_t)t * (E / 4) * B + b;
#pragma unroll 4
        for (int e4 = 0; e4 < E / 4; ++e4) {
            float4 xv = xp[(size_t)e4 * B];
            int s = e4 * 4;
            a0 += wu0[s] * xv.x; a0 += wu0[s + 1] * xv.y; a0 += wu0[s + 2] * xv.z; a0 += wu0[s + 3] * xv.w;
            a1 += wu1[s] * xv.x; a1 += wu1[s + 1] * xv.y; a1 += wu1[s + 2] * xv.z; a1 += wu1[s + 3] * xv.w;
            a2 += wu2[s] * xv.x; a2 += wu2[s + 1] * xv.y; a2 += wu2[s + 2] * xv.z; a2 += wu2[s + 3] * xv.w;
            a3 += wu3[s] * xv.x; a3 += wu3[s + 1] * xv.y; a3 += wu3[s + 2] * xv.z; a3 += wu3[s + 3] * xv.w;
        }
#pragma unroll 4
        for (int r4 = 0; r4 < 16; ++r4) {
            float4 hv = hs_in[(size_t)r4 * B];
            int s = E + r4 * 4;
            a0 += wu0[s] * hv.x; a0 += wu0[s + 1] * hv.y; a0 += wu0[s + 2] * hv.z; a0 += wu0[s + 3] * hv.w;
            a1 += wu1[s] * hv.x; a1 += wu1[s + 1] * hv.y; a1 += wu1[s + 2] * hv.z; a1 += wu1[s + 3] * hv.w;
            a2 += wu2[s] * hv.x; a2 += wu2[s + 1] * hv.y; a2 += wu2[s + 2] * hv.z; a2 += wu2[s + 3] * hv.w;
            a3 += wu3[s] * hv.x; a3 += wu3[s + 1] * hv.y; a3 += wu3[s + 2] * hv.z; a3 += wu3[s + 3] * hv.w;
        }
    } else {
#pragma unroll 4
        for (int r4 = 16; r4 < 64; ++r4) {
            float4 hv = hs_in[(size_t)r4 * B];
            int s = E + r4 * 4;
            a0 += wu0[s] * hv.x; a0 += wu0[s + 1] * hv.y; a0 += wu0[s + 2] * hv.z; a0 += wu0[s + 3] * hv.w;
            a1 += wu1[s] * hv.x; a1 += wu1[s + 1] * hv.y; a1 += wu1[s + 2] * hv.z; a1 += wu1[s + 3] * hv.w;
            a2 += wu2[s] * hv.x; a2 += wu2[s + 1] * hv.y; a2 += wu2[s + 2] * hv.z; a2 += wu2[s + 3] * hv.w;
            a3 += wu3[s] * hv.x; a3 += wu3[s + 1] * hv.y; a3 += wu3[s + 2] * hv.z; a3 += wu3[s + 3] * hv.w;
        }
        partial[rl][0][lane] = a0;
        partial[rl][1][lane] = a1;
        partial[rl][2][lane] = a2;
        partial[rl][3][lane] = a3;
    }
    __syncthreads();
    if (k == 0) {
        a0 += partial[rl][0][lane];
        a1 += partial[rl][1][lane];
        a2 += partial[rl][2][lane];
        a3 += partial[rl][3][lane];
        float ii = 1.f / (1.f + expf(-a0));
        float ff = 1.f / (1.f + expf(-a1));
        float gg = tanhf(a2);
        float oo = 1.f / (1.f + expf(-a3));
        float cold = cbuf[(size_t)r * B + b];
        float cn = ff * cold + ii * gg;
        float hn = oo * tanhf(cn);
        cbuf[(size_t)r * B + b] = cn;
        HS[((size_t)(t + 1) * (R / 4) + (r >> 2)) * (B * 4) + (size_t)b * 4 + (r & 3)] = hn;
        if (t == S - 1) {
            out[HOUT_OFF + (size_t)b * R + r] = hn;
            out[COUT_OFF + (size_t)b * R + r] = cn;
        }
    }
}

// probs[b][t][c] = softmax(h_t @ Wout + bout).  grid = dim3(S, 2), block = 64.
__global__ void out_probs(const float* __restrict__ HS, const float* __restrict__ Wout,
                          const float* __restrict__ bout, float* __restrict__ out) {
    int t    = blockIdx.x;
    int bg   = blockIdx.y;
    int lane = threadIdx.x;          // 64
    int b    = bg * 64 + lane;
    float acc[9];
#pragma unroll
    for (int c = 0; c < 9; ++c) acc[c] = bout[c];
    const float4* hp = (const float4*)HS + (size_t)(t + 1) * (R / 4) * B + b;
#pragma unroll 4
    for (int r4 = 0; r4 < R / 4; ++r4) {
        float4 hv = hp[(size_t)r4 * B];
        int r = r4 * 4;
#pragma unroll
        for (int c = 0; c < 9; ++c) {
            acc[c] += hv.x * Wout[(size_t)(r + 0) * 9 + c];
            acc[c] += hv.y * Wout[(size_t)(r + 1) * 9 + c];
            acc[c] += hv.z * Wout[(size_t)(r + 2) * 9 + c];
            acc[c] += hv.w * Wout[(size_t)(r + 3) * 9 + c];
        }
    }
    float m = acc[0];
#pragma unroll
    for (int c = 1; c < 9; ++c) m = fmaxf(m, acc[c]);
    float e[9];
    float sum = 0.f;
#pragma unroll
    for (int c = 0; c < 9; ++c) { e[c] = expf(acc[c] - m); sum += e[c]; }
    float inv = 1.f / sum;
#pragma unroll
    for (int c = 0; c < 9; ++c) out[((size_t)b * S + t) * 9 + c] = e[c] * inv;
}

extern "C" void kernel_launch(void* const* d_in, const int* in_sizes, int n_in,
                              void* d_out, int out_size, void* d_ws, size_t ws_size,
                              hipStream_t stream) {
    const int*   idx   = (const int*)d_in[0];
    const float* embed = (const float*)d_in[1];
    const float* W     = (const float*)d_in[2];
    const float* U     = (const float*)d_in[3];
    const float* bias  = (const float*)d_in[4];
    const float* Wout  = (const float*)d_in[5];
    const float* bout  = (const float*)d_in[6];
    float*       out   = (float*)d_out;
    float*       ws    = (float*)d_ws;

    if (ws_size < WS_FLOATS * sizeof(float)) return;  // workspace too small: fail loudly

    float*  HS   = ws;
    float*  cbuf = ws + C_OFF;
    float4* X4   = (float4*)(ws + X4_OFF);
    float*  WUt  = ws + WUT_OFF;

    zero_state<<<64, 256, 0, stream>>>((float4*)HS, (float4*)cbuf);
    gather_x<<<S, 256, 0, stream>>>(idx, embed, X4);
    make_wut<<<G4, 384, 0, stream>>>(W, U, WUt);
    for (int t = 0; t < S; ++t)
        lstm_step<<<dim3(R / 2, 2), 256, 0, stream>>>(X4, WUt, bias, HS, cbuf, out, t);
    out_probs<<<dim3(S, 2), 64, 0, stream>>>(HS, Wout, bout, out);
}